// Round 1
// baseline (82.918 us; speedup 1.0000x reference)
//
#include <hip/hip_runtime.h>

#define NDIM 1024
#define BDIM 128
#define TS 32
#define NT (NDIM / TS)                  // 32 tile-rows
#define NTILES (NT * (NT + 1) / 2)      // 528 upper-tri tiles

// ---------------- stage 1: per-tile partial sums ----------------
__global__ __launch_bounds__(256) void potts_stage1(
    const float* __restrict__ V,      // [B][N] row-major
    const float* __restrict__ W,      // [N][N] row-major
    float* __restrict__ partial)      // [NTILES][B]
{
    const int t = blockIdx.x;
    // decode linear upper-tri tile index -> (ti, tj), ti <= tj
    // tiles before row r: g(r) = NT*r - r*(r-1)/2
    int ti = (int)((2.0 * NT + 1.0 - sqrt((2.0 * NT + 1.0) * (2.0 * NT + 1.0) - 8.0 * t)) * 0.5);
    if (ti < 0) ti = 0;
    while ((NT * (ti + 1) - (ti + 1) * ti / 2) <= t) ++ti;
    while ((NT * ti - ti * (ti - 1) / 2) > t) --ti;
    const int tj = ti + (t - (NT * ti - ti * (ti - 1) / 2));
    const int I0 = ti * TS, J0 = tj * TS;
    const bool diag = (ti == tj);

    __shared__ float vI[TS][BDIM + 1];  // stride 129 words -> conflict-free transpose
    __shared__ float vJ[TS][BDIM + 1];
    __shared__ float red[256];

    const int tid = threadIdx.x;

    // Transposed staging of V slices: coalesced global reads, padded LDS writes.
    for (int idx = tid; idx < TS * BDIM; idx += 256) {
        const int j = idx & (TS - 1);
        const int b = idx >> 5;
        vJ[j][b] = V[b * NDIM + J0 + j];
        vI[j][b] = V[b * NDIM + I0 + j];
    }
    __syncthreads();

    const int b = tid & (BDIM - 1);
    // force wave-uniform so W addressing stays scalar (s_load path)
    const int half = __builtin_amdgcn_readfirstlane(tid >> 7);

    float vj[TS];
#pragma unroll
    for (int j = 0; j < TS; ++j) vj[j] = vJ[j][b];

    float acc0 = 0.f, acc1 = 0.f, acc2 = 0.f, acc3 = 0.f;

    for (int ii = 0; ii < TS / 2; ++ii) {
        const int iloc = half * (TS / 2) + ii;          // wave-uniform
        const float vi = vI[iloc][b];
        const float q = 1.0f - vi;
        const float r = 2.0f * vi - 1.0f;
        const float* __restrict__ wrow = W + (size_t)(I0 + iloc) * NDIM + J0;
#pragma unroll
        for (int j = 0; j < TS; j += 4) {
            float w0 = wrow[j + 0];
            float w1 = wrow[j + 1];
            float w2 = wrow[j + 2];
            float w3 = wrow[j + 3];
            if (diag) {  // uniform: scalar selects, zero VALU cost
                if (j + 0 < iloc) w0 = 0.0f;
                if (j + 1 < iloc) w1 = 0.0f;
                if (j + 2 < iloc) w2 = 0.0f;
                if (j + 3 < iloc) w3 = 0.0f;
            }
            acc0 = fmaf(w0, fmaf(r, vj[j + 0], q), acc0);
            acc1 = fmaf(w1, fmaf(r, vj[j + 1], q), acc1);
            acc2 = fmaf(w2, fmaf(r, vj[j + 2], q), acc2);
            acc3 = fmaf(w3, fmaf(r, vj[j + 3], q), acc3);
        }
    }

    const float acc = (acc0 + acc1) + (acc2 + acc3);

    // combine half 0 + half 1 for each b, then one coalesced store per tile
    red[tid] = acc;
    __syncthreads();
    if (tid < BDIM) {
        partial[t * BDIM + tid] = red[tid] + red[tid + BDIM];
    }
}

// ---------------- stage 2: reduce tiles -> out[b] ----------------
__global__ __launch_bounds__(64) void potts_stage2(
    const float* __restrict__ partial, float* __restrict__ out)
{
    const int b = blockIdx.x;
    const int lane = threadIdx.x;
    float acc = 0.f;
    for (int t = lane; t < NTILES; t += 64)
        acc += partial[t * BDIM + b];
#pragma unroll
    for (int off = 32; off > 0; off >>= 1)
        acc += __shfl_down(acc, off);
    if (lane == 0) out[b] = acc;
}

extern "C" void kernel_launch(void* const* d_in, const int* in_sizes, int n_in,
                              void* d_out, int out_size, void* d_ws, size_t ws_size,
                              hipStream_t stream) {
    const float* V = (const float*)d_in[0];   // vector  [128][1024]
    const float* W = (const float*)d_in[1];   // interactions [1024][1024]
    float* out = (float*)d_out;               // [128]
    float* partial = (float*)d_ws;            // [528][128] = 270336 B

    potts_stage1<<<dim3(NTILES), dim3(256), 0, stream>>>(V, W, partial);
    potts_stage2<<<dim3(BDIM), dim3(64), 0, stream>>>(partial, out);
}